// Round 2
// baseline (12695.065 us; speedup 1.0000x reference)
//
#include <hip/hip_runtime.h>
#include <hip/hip_bf16.h>
#include <hip/hip_cooperative_groups.h>

namespace cg = cooperative_groups;

typedef __bf16 bf16x8 __attribute__((ext_vector_type(8)));
typedef float floatx4 __attribute__((ext_vector_type(4)));

#define GLD_LDS16(g, s)                                              \
  __builtin_amdgcn_global_load_lds(                                  \
      (__attribute__((address_space(1))) void*)(g),                  \
      (__attribute__((address_space(3))) void*)(s), 16, 0, 0)

constexpr int B_ = 128, S_ = 256, E_ = 512, H_ = 1024, V_ = 2048;
constexpr int KC_ = E_ + H_;  // 1536 combined contraction dim [x | h]

// ---- dtype detect: count bf16-decoded values >= 1.0 in first 64KB of emb.
// bf16 data (~N(0,0.02^2)) -> 0 such values. fp32 data read as bf16 ->
// ~half of the low-mantissa words decode huge. flag=1 => inputs are fp32.
__global__ void k_detect(const unsigned short* __restrict__ emb,
                         int* __restrict__ flag) {
  __shared__ int cnt;
  if (threadIdx.x == 0) cnt = 0;
  __syncthreads();
  int local = 0;
  for (int i = threadIdx.x; i < 32768; i += 256) {
    unsigned int u = ((unsigned int)emb[i]) << 16;
    float v = __uint_as_float(u);
    if (!(fabsf(v) < 1.0f)) local++;  // catches big + inf + NaN
  }
  atomicAdd(&cnt, local);
  __syncthreads();
  if (threadIdx.x == 0) flag[0] = (cnt > 256) ? 1 : 0;
}

// ---- biases -> fp32 in ws: [bf(4096) | bb(4096) | bd(2048)]
__global__ void k_bias(const void* __restrict__ bfv, const void* __restrict__ bbv,
                       const void* __restrict__ bdv, float* __restrict__ biasws,
                       const int* __restrict__ flag) {
  bool f32 = flag[0] != 0;
  int i = blockIdx.x * 256 + threadIdx.x;
  if (i >= 10240) return;
  const void* src;
  int off;
  if (i < 4096) { src = bfv; off = i; }
  else if (i < 8192) { src = bbv; off = i - 4096; }
  else { src = bdv; off = i - 8192; }
  float v = f32 ? ((const float*)src)[off]
                : __bfloat162float(((const __hip_bfloat16*)src)[off]);
  biasws[i] = v;
}

// ---- gather: xt[s][b][e] = bf16(emb[tokens[b][s]][e]) ----
__global__ void k_gather(const int* __restrict__ tokens, const void* __restrict__ emb,
                         __hip_bfloat16* __restrict__ xt,
                         const int* __restrict__ flag) {
  bool f32 = flag[0] != 0;
  int idx = blockIdx.x * 256 + threadIdx.x;  // one 16B-out chunk (8 bf16)
  int e8 = idx & 63;                         // E/8 = 64 chunks per row
  int sb = idx >> 6;                         // s*128 + b
  int s = sb >> 7;
  int b = sb & 127;
  int tok = tokens[b * S_ + s];
  uint4* dst = (uint4*)(xt + (size_t)sb * E_) + e8;
  if (f32) {
    const float* src = (const float*)emb + (size_t)tok * E_ + e8 * 8;
    float4 lo = ((const float4*)src)[0];
    float4 hi = ((const float4*)src)[1];
    __hip_bfloat16 v[8];
    v[0] = __float2bfloat16(lo.x); v[1] = __float2bfloat16(lo.y);
    v[2] = __float2bfloat16(lo.z); v[3] = __float2bfloat16(lo.w);
    v[4] = __float2bfloat16(hi.x); v[5] = __float2bfloat16(hi.y);
    v[6] = __float2bfloat16(hi.z); v[7] = __float2bfloat16(hi.w);
    *dst = *(const uint4*)v;
  } else {
    *dst = ((const uint4*)((const __hip_bfloat16*)emb + (size_t)tok * E_))[e8];
  }
}

// ---- transpose: out[n][ocol + k] = bf16(in[k][n]) ----
__global__ void k_transpose(const void* __restrict__ in, int K, int N,
                            __hip_bfloat16* __restrict__ out, int ostride,
                            int ocol, const int* __restrict__ flag) {
  bool f32 = flag[0] != 0;
  __shared__ __hip_bfloat16 tile[64][65];
  int n0 = blockIdx.x * 64, k0 = blockIdx.y * 64;
  for (int i = 0; i < 16; ++i) {
    int flat = i * 256 + threadIdx.x;
    int kk = flat >> 6, nn = flat & 63;
    size_t off = (size_t)(k0 + kk) * N + n0 + nn;
    tile[kk][nn] = f32 ? __float2bfloat16(((const float*)in)[off])
                       : ((const __hip_bfloat16*)in)[off];
  }
  __syncthreads();
  for (int i = 0; i < 16; ++i) {
    int flat = i * 256 + threadIdx.x;
    int nn = flat >> 6, kk = flat & 63;
    out[(size_t)(n0 + nn) * ostride + ocol + k0 + kk] = tile[kk][nn];
  }
}

// ---- persistent bidirectional LSTM ----
// grid = 128 blocks: 0..63 forward (tanh), 64..127 backward (relu).
// Block (dir, nb) owns h-units j0..j0+15 -> 64 z-cols (4 gates x 16).
// Per step: z = [x_t | h_prev] @ WT^T  (M=128, N=64, K=1536; K=512 at t=0
// since h0=0), gate epilogue updates c (fp32) and writes h bf16 into
// hcat[t][b][dir*H + j]. One grid.sync per step.
__global__ void __launch_bounds__(256, 1)
k_lstm(const __hip_bfloat16* __restrict__ xt,
       const __hip_bfloat16* __restrict__ WTf,
       const __hip_bfloat16* __restrict__ WTb,
       const float* __restrict__ biasf, const float* __restrict__ biasb,
       __hip_bfloat16* __restrict__ hcat, float* __restrict__ cbuf) {
  cg::grid_group grid = cg::this_grid();
  __shared__ __align__(16) unsigned char smem[32768];
  __hip_bfloat16* At = (__hip_bfloat16*)smem;           // [128][32] 8KB
  __hip_bfloat16* Bt = (__hip_bfloat16*)(smem + 8192);  // [64][32]  4KB
  float* zt = (float*)smem;                             // [128][64] 32KB (reuse)

  const int tid = threadIdx.x;
  const int lane = tid & 63, wave = tid >> 6;
  const int dir = blockIdx.x >> 6;
  const int nb = blockIdx.x & 63;
  const int j0 = nb * 16;
  const __hip_bfloat16* WT = dir ? WTb : WTf;
  const float* bias = dir ? biasb : biasf;
  const int wr = wave >> 1, wc = wave & 1;  // wave: rows wr*64, cols wc*32

  // A staging: 2 x 16B per thread; dest byte (wave*2+q)*1024 + lane*16
  int arow[2], akoff[2];
  for (int q = 0; q < 2; ++q) {
    int flat = (wave * 2 + q) * 1024 + lane * 16;
    arow[q] = flat >> 6;         // tile row (ld = 64B = 32 elems)
    akoff[q] = (flat & 63) >> 1; // k offset in elements
  }
  // B staging: 1 x 16B per thread; tile row r -> weight row (r>>4)*H + j0 + (r&15)
  int bflat = wave * 1024 + lane * 16;
  int br = bflat >> 6;
  int bkoff = (bflat & 63) >> 1;
  const __hip_bfloat16* Bsrc_row =
      WT + (size_t)((br >> 4) * H_ + j0 + (br & 15)) * KC_;

  float* crow = cbuf + (size_t)dir * B_ * H_;

  for (int t = 0; t < S_; ++t) {
    const int t_in = dir ? (S_ - 1 - t) : t;
    const int t_prev = dir ? (t_in + 1) : (t_in - 1);

    floatx4 acc[4][2] = {};

    const __hip_bfloat16* xbase = xt + (size_t)t_in * B_ * E_;
    const __hip_bfloat16* hbase =
        hcat + (size_t)t_prev * B_ * 2 * H_ + dir * H_;
    const int kcn = (t == 0) ? 16 : 48;  // h0 == 0: skip h half at t=0

    for (int kc = 0; kc < kcn; ++kc) {
      const __hip_bfloat16* Ab;
      int astride, kloc;
      if (kc < 16) {
        Ab = xbase; astride = E_; kloc = kc * 32;
      } else {
        Ab = hbase; astride = 2 * H_; kloc = (kc - 16) * 32;
      }
      for (int q = 0; q < 2; ++q) {
        const __hip_bfloat16* src = Ab + (size_t)arow[q] * astride + kloc + akoff[q];
        GLD_LDS16(src, At + (wave * 2 + q) * 512);
      }
      {
        const __hip_bfloat16* src = Bsrc_row + kc * 32 + bkoff;
        GLD_LDS16(src, Bt + wave * 512);
      }
      __syncthreads();
      bf16x8 a[4], b[2];
      const int k8 = (lane >> 4) * 8;
      for (int i = 0; i < 4; ++i) {
        int m = wr * 64 + i * 16 + (lane & 15);
        a[i] = *(const bf16x8*)((const char*)At + m * 64 + k8 * 2);
      }
      for (int j = 0; j < 2; ++j) {
        int n = wc * 32 + j * 16 + (lane & 15);
        b[j] = *(const bf16x8*)((const char*)Bt + n * 64 + k8 * 2);
      }
      for (int i = 0; i < 4; ++i)
        for (int j = 0; j < 2; ++j)
          acc[i][j] =
              __builtin_amdgcn_mfma_f32_16x16x32_bf16(a[i], b[j], acc[i][j], 0, 0, 0);
      __syncthreads();
    }

    // acc -> zt (fp32 [128 batch][64 cols], col = gate*16 + unit)
    for (int i = 0; i < 4; ++i)
      for (int j = 0; j < 2; ++j)
        for (int r = 0; r < 4; ++r) {
          int m = wr * 64 + i * 16 + (lane >> 4) * 4 + r;
          int n = wc * 32 + j * 16 + (lane & 15);
          zt[m * 64 + n] = acc[i][j][r];
        }
    __syncthreads();

    __hip_bfloat16* hout = hcat + (size_t)t_in * B_ * 2 * H_ + dir * H_;
    for (int p = tid; p < B_ * 16; p += 256) {
      int b_ = p >> 4, jj = p & 15;
      float zi = zt[b_ * 64 + jj] + bias[j0 + jj];
      float zf = zt[b_ * 64 + 16 + jj] + bias[H_ + j0 + jj];
      float zg = zt[b_ * 64 + 32 + jj] + bias[2 * H_ + j0 + jj];
      float zo = zt[b_ * 64 + 48 + jj] + bias[3 * H_ + j0 + jj];
      float iv = 1.f / (1.f + expf(-zi));
      float fv = 1.f / (1.f + expf(-zf));
      float ov = 1.f / (1.f + expf(-zo));
      float gv = dir ? fmaxf(zg, 0.f) : tanhf(zg);
      float c_old = (t == 0) ? 0.f : crow[b_ * H_ + j0 + jj];
      float c = fv * c_old + iv * gv;
      crow[b_ * H_ + j0 + jj] = c;
      float hv = ov * (dir ? fmaxf(c, 0.f) : tanhf(c));
      hout[(size_t)b_ * 2 * H_ + j0 + jj] = __float2bfloat16(hv);
    }
    grid.sync();
  }
}

// ---- dense: out[b][s][v] = hcat[s][b][:] @ Wd + bd ----
__global__ void __launch_bounds__(256, 1)
k_dense(const __hip_bfloat16* __restrict__ hcat,
        const __hip_bfloat16* __restrict__ WdT, const float* __restrict__ bd,
        void* __restrict__ outv, const int* __restrict__ flag) {
  bool f32 = flag[0] != 0;
  __shared__ __align__(16) unsigned char smem[16384];
  __hip_bfloat16* At = (__hip_bfloat16*)smem;           // [128][32]
  __hip_bfloat16* Bt = (__hip_bfloat16*)(smem + 8192);  // [128][32]
  const int tid = threadIdx.x, lane = tid & 63, wave = tid >> 6;
  const int wr = wave >> 1, wc = wave & 1;  // wave: rows wr*64, cols wc*64
  const int r0 = blockIdx.x * 128;          // rows (s*128+b)
  const int n0 = blockIdx.y * 128;          // vocab cols

  floatx4 acc[4][4] = {};
  int arow[2], akoff[2];
  for (int q = 0; q < 2; ++q) {
    int flat = (wave * 2 + q) * 1024 + lane * 16;
    arow[q] = flat >> 6;
    akoff[q] = (flat & 63) >> 1;
  }

  for (int kc = 0; kc < 64; ++kc) {
    for (int q = 0; q < 2; ++q) {
      const __hip_bfloat16* srcA =
          hcat + (size_t)(r0 + arow[q]) * 2048 + kc * 32 + akoff[q];
      GLD_LDS16(srcA, At + (wave * 2 + q) * 512);
      const __hip_bfloat16* srcB =
          WdT + (size_t)(n0 + arow[q]) * 2048 + kc * 32 + akoff[q];
      GLD_LDS16(srcB, Bt + (wave * 2 + q) * 512);
    }
    __syncthreads();
    bf16x8 a[4], b[4];
    const int k8 = (lane >> 4) * 8;
    for (int i = 0; i < 4; ++i) {
      int m = wr * 64 + i * 16 + (lane & 15);
      a[i] = *(const bf16x8*)((const char*)At + m * 64 + k8 * 2);
    }
    for (int j = 0; j < 4; ++j) {
      int n = wc * 64 + j * 16 + (lane & 15);
      b[j] = *(const bf16x8*)((const char*)Bt + n * 64 + k8 * 2);
    }
    for (int i = 0; i < 4; ++i)
      for (int j = 0; j < 4; ++j)
        acc[i][j] =
            __builtin_amdgcn_mfma_f32_16x16x32_bf16(a[i], b[j], acc[i][j], 0, 0, 0);
    __syncthreads();
  }

  for (int j = 0; j < 4; ++j) {
    int n = n0 + wc * 64 + j * 16 + (lane & 15);
    float bdv = bd[n];
    for (int i = 0; i < 4; ++i)
      for (int r = 0; r < 4; ++r) {
        int m = wr * 64 + i * 16 + (lane >> 4) * 4 + r;
        int row = r0 + m;
        int s = row >> 7, b_ = row & 127;
        size_t off = (size_t)b_ * S_ * V_ + (size_t)s * V_ + n;
        float val = acc[i][j][r] + bdv;
        if (f32)
          ((float*)outv)[off] = val;
        else
          ((__hip_bfloat16*)outv)[off] = __float2bfloat16(val);
      }
  }
}

extern "C" void kernel_launch(void* const* d_in, const int* in_sizes, int n_in,
                              void* d_out, int out_size, void* d_ws,
                              size_t ws_size, hipStream_t stream) {
  const int* tokens = (const int*)d_in[0];
  const void* emb = d_in[1];
  const void* Wf = d_in[2];
  const void* Uf = d_in[3];
  const void* bfv = d_in[4];
  const void* Wb = d_in[5];
  const void* Ub = d_in[6];
  const void* bbv = d_in[7];
  const void* Wd = d_in[8];
  const void* bd = d_in[9];

  char* ws = (char*)d_ws;
  int* flag = (int*)ws;                                        // 256 B
  float* biasws = (float*)(ws + 256);                          // 10240 f32 = 40KB
  __hip_bfloat16* WTf = (__hip_bfloat16*)(ws + 256 + 40960);   // [4096][1536]
  __hip_bfloat16* WTb = WTf + (size_t)4096 * 1536;             // [4096][1536]
  __hip_bfloat16* WdT = WTb + (size_t)4096 * 1536;             // [2048][2048]
  __hip_bfloat16* xt = WdT + (size_t)2048 * 2048;              // [256][128][512]
  __hip_bfloat16* hcat = xt + (size_t)S_ * B_ * E_;            // [256][128][2048]
  float* cbuf = (float*)(hcat + (size_t)S_ * B_ * 2 * H_);     // [2][128][1024] f32

  k_detect<<<1, 256, 0, stream>>>((const unsigned short*)emb, flag);
  k_bias<<<40, 256, 0, stream>>>(bfv, bbv, bd, biasws, flag);
  k_gather<<<8192, 256, 0, stream>>>(tokens, emb, xt, flag);
  k_transpose<<<dim3(64, 8), 256, 0, stream>>>(Wf, 512, 4096, WTf, KC_, 0, flag);
  k_transpose<<<dim3(64, 16), 256, 0, stream>>>(Uf, 1024, 4096, WTf, KC_, 512, flag);
  k_transpose<<<dim3(64, 8), 256, 0, stream>>>(Wb, 512, 4096, WTb, KC_, 0, flag);
  k_transpose<<<dim3(64, 16), 256, 0, stream>>>(Ub, 1024, 4096, WTb, KC_, 512, flag);
  k_transpose<<<dim3(32, 32), 256, 0, stream>>>(Wd, 2048, 2048, WdT, 2048, 0, flag);

  float* biasf_ws = biasws;
  float* biasb_ws = biasws + 4096;
  float* bd_ws = biasws + 8192;
  void* args[] = {(void*)&xt,       (void*)&WTf,      (void*)&WTb,
                  (void*)&biasf_ws, (void*)&biasb_ws, (void*)&hcat,
                  (void*)&cbuf};
  hipLaunchCooperativeKernel((void*)k_lstm, dim3(128), dim3(256), args, 0,
                             stream);

  k_dense<<<dim3(256, 16), 256, 0, stream>>>(hcat, WdT, bd_ws, d_out, flag);
}

// Round 3
// 8704.401 us; speedup vs baseline: 1.4585x; 1.4585x over previous
//
#include <hip/hip_runtime.h>
#include <hip/hip_bf16.h>
#include <hip/hip_cooperative_groups.h>

namespace cg = cooperative_groups;

typedef __bf16 bf16x8 __attribute__((ext_vector_type(8)));
typedef float floatx4 __attribute__((ext_vector_type(4)));

#define GLD_LDS16(g, s)                                              \
  __builtin_amdgcn_global_load_lds(                                  \
      (__attribute__((address_space(1))) void*)(g),                  \
      (__attribute__((address_space(3))) void*)(s), 16, 0, 0)

#define MFMA16(a, b, c) __builtin_amdgcn_mfma_f32_16x16x32_bf16(a, b, c, 0, 0, 0)

constexpr int B_ = 128, S_ = 256, E_ = 512, H_ = 1024, V_ = 2048;
constexpr int KC_ = E_ + H_;  // 1536 combined contraction dim [x | h]

// ---- dtype detect: count bf16-decoded values >= 1.0 in first 64KB of emb.
__global__ void k_detect(const unsigned short* __restrict__ emb,
                         int* __restrict__ flag) {
  __shared__ int cnt;
  if (threadIdx.x == 0) cnt = 0;
  __syncthreads();
  int local = 0;
  for (int i = threadIdx.x; i < 32768; i += 256) {
    unsigned int u = ((unsigned int)emb[i]) << 16;
    float v = __uint_as_float(u);
    if (!(fabsf(v) < 1.0f)) local++;
  }
  atomicAdd(&cnt, local);
  __syncthreads();
  if (threadIdx.x == 0) flag[0] = (cnt > 256) ? 1 : 0;
}

// ---- biases -> fp32 in ws: [bf(4096) | bb(4096) | bd(2048)]
__global__ void k_bias(const void* __restrict__ bfv, const void* __restrict__ bbv,
                       const void* __restrict__ bdv, float* __restrict__ biasws,
                       const int* __restrict__ flag) {
  bool f32 = flag[0] != 0;
  int i = blockIdx.x * 256 + threadIdx.x;
  if (i >= 10240) return;
  const void* src;
  int off;
  if (i < 4096) { src = bfv; off = i; }
  else if (i < 8192) { src = bbv; off = i - 4096; }
  else { src = bdv; off = i - 8192; }
  float v = f32 ? ((const float*)src)[off]
                : __bfloat162float(((const __hip_bfloat16*)src)[off]);
  biasws[i] = v;
}

// ---- gather: xt[s][b][e] = bf16(emb[tokens[b][s]][e]) ----
__global__ void k_gather(const int* __restrict__ tokens, const void* __restrict__ emb,
                         __hip_bfloat16* __restrict__ xt,
                         const int* __restrict__ flag) {
  bool f32 = flag[0] != 0;
  int idx = blockIdx.x * 256 + threadIdx.x;
  int e8 = idx & 63;
  int sb = idx >> 6;
  int s = sb >> 7;
  int b = sb & 127;
  int tok = tokens[b * S_ + s];
  uint4* dst = (uint4*)(xt + (size_t)sb * E_) + e8;
  if (f32) {
    const float* src = (const float*)emb + (size_t)tok * E_ + e8 * 8;
    float4 lo = ((const float4*)src)[0];
    float4 hi = ((const float4*)src)[1];
    __hip_bfloat16 v[8];
    v[0] = __float2bfloat16(lo.x); v[1] = __float2bfloat16(lo.y);
    v[2] = __float2bfloat16(lo.z); v[3] = __float2bfloat16(lo.w);
    v[4] = __float2bfloat16(hi.x); v[5] = __float2bfloat16(hi.y);
    v[6] = __float2bfloat16(hi.z); v[7] = __float2bfloat16(hi.w);
    *dst = *(const uint4*)v;
  } else {
    *dst = ((const uint4*)((const __hip_bfloat16*)emb + (size_t)tok * E_))[e8];
  }
}

// ---- transpose: out[n][ocol + k] = bf16(in[k][n]) ----
__global__ void k_transpose(const void* __restrict__ in, int K, int N,
                            __hip_bfloat16* __restrict__ out, int ostride,
                            int ocol, const int* __restrict__ flag) {
  bool f32 = flag[0] != 0;
  __shared__ __hip_bfloat16 tile[64][65];
  int n0 = blockIdx.x * 64, k0 = blockIdx.y * 64;
  for (int i = 0; i < 16; ++i) {
    int flat = i * 256 + threadIdx.x;
    int kk = flat >> 6, nn = flat & 63;
    size_t off = (size_t)(k0 + kk) * N + n0 + nn;
    tile[kk][nn] = f32 ? __float2bfloat16(((const float*)in)[off])
                       : ((const __hip_bfloat16*)in)[off];
  }
  __syncthreads();
  for (int i = 0; i < 16; ++i) {
    int flat = i * 256 + threadIdx.x;
    int nn = flat >> 6, kk = flat & 63;
    out[(size_t)(n0 + nn) * ostride + ocol + k0 + kk] = tile[kk][nn];
  }
}

// ---- persistent bidirectional LSTM, weight-stationary ----
// 256 blocks: 0..127 fwd (tanh), 128..255 bwd (relu). Block owns 8 h-units
// (32 z-cols = 4 gates x 8 units). Weights [32][1536] live in LDS in MFMA
// fragment order (loaded once). Per step: z = [x_t | h_prev] @ W^T with
// M=128, N=32; A fragments stream global->VGPR (no barriers in K loop).
// c state in registers; h written bf16 to hcat; per-direction barrier.
__global__ void __launch_bounds__(256, 1)
k_lstm(const __hip_bfloat16* __restrict__ xt,
       const __hip_bfloat16* __restrict__ WTf,
       const __hip_bfloat16* __restrict__ WTb,
       const float* __restrict__ biasf, const float* __restrict__ biasb,
       __hip_bfloat16* __restrict__ hcat, int* __restrict__ ctr0,
       int* __restrict__ ctr1) {
  extern __shared__ __align__(16) unsigned char smem[];
  __hip_bfloat16* Blds = (__hip_bfloat16*)smem;  // 96 frags x 1KB = 96KB
  float* ztf = (float*)(smem + 98304);           // 16 frags x 1KB = 16KB

  const int tid = threadIdx.x, lane = tid & 63, wave = tid >> 6;
  const int dir = blockIdx.x >> 7;
  const int nb = blockIdx.x & 127;
  const int j0 = nb * 8;
  const __hip_bfloat16* WT = dir ? WTb : WTf;
  const float* bias = dir ? biasb : biasf;
  int* ctr = dir ? ctr1 : ctr0;

  // ---- stage weights into LDS, fragment order (source is per-lane scatter)
  for (int f = wave; f < 96; f += 4) {
    int kc = f >> 1, j = f & 1;
    int c = j * 16 + (lane & 15);              // block-local col 0..31
    int row = (c >> 3) * H_ + j0 + (c & 7);    // gate*H + unit
    const __hip_bfloat16* src =
        WT + (size_t)row * KC_ + kc * 32 + ((lane >> 4) * 8);
    GLD_LDS16(src, (char*)Blds + (size_t)f * 1024);
  }

  const int jj = tid & 7;
  const float bi = bias[j0 + jj];
  const float bf2 = bias[H_ + j0 + jj];
  const float bg = bias[2 * H_ + j0 + jj];
  const float bo = bias[3 * H_ + j0 + jj];
  float creg[4] = {0.f, 0.f, 0.f, 0.f};

  const int m0 = wave * 32 + (lane & 15);  // wave's M strip: rows 32w..32w+31
  const int k8 = (lane >> 4) * 8;
  __syncthreads();  // drains weight staging vmcnt

  for (int t = 0; t < S_; ++t) {
    const int t_in = dir ? (S_ - 1 - t) : t;
    const int t_prev = dir ? (t_in + 1) : (t_in - 1);

    floatx4 acc[2][2] = {};

    const __hip_bfloat16* xb = xt + (size_t)t_in * B_ * E_;
#pragma unroll 4
    for (int kc = 0; kc < 16; ++kc) {
      bf16x8 a0 = *(const bf16x8*)(xb + (size_t)m0 * E_ + kc * 32 + k8);
      bf16x8 a1 = *(const bf16x8*)(xb + (size_t)(m0 + 16) * E_ + kc * 32 + k8);
      bf16x8 b0 = *(const bf16x8*)((char*)Blds + (kc * 2 + 0) * 1024 + lane * 16);
      bf16x8 b1 = *(const bf16x8*)((char*)Blds + (kc * 2 + 1) * 1024 + lane * 16);
      acc[0][0] = MFMA16(a0, b0, acc[0][0]);
      acc[0][1] = MFMA16(a0, b1, acc[0][1]);
      acc[1][0] = MFMA16(a1, b0, acc[1][0]);
      acc[1][1] = MFMA16(a1, b1, acc[1][1]);
    }
    if (t > 0) {
      const __hip_bfloat16* hb =
          hcat + (size_t)t_prev * B_ * 2 * H_ + dir * H_;
#pragma unroll 4
      for (int kc = 0; kc < 32; ++kc) {
        bf16x8 a0 = *(const bf16x8*)(hb + (size_t)m0 * 2 * H_ + kc * 32 + k8);
        bf16x8 a1 =
            *(const bf16x8*)(hb + (size_t)(m0 + 16) * 2 * H_ + kc * 32 + k8);
        bf16x8 b0 =
            *(const bf16x8*)((char*)Blds + ((16 + kc) * 2 + 0) * 1024 + lane * 16);
        bf16x8 b1 =
            *(const bf16x8*)((char*)Blds + ((16 + kc) * 2 + 1) * 1024 + lane * 16);
        acc[0][0] = MFMA16(a0, b0, acc[0][0]);
        acc[0][1] = MFMA16(a0, b1, acc[0][1]);
        acc[1][0] = MFMA16(a1, b0, acc[1][0]);
        acc[1][1] = MFMA16(a1, b1, acc[1][1]);
      }
    }

    // acc -> LDS, fragment order (ds_write_b128, conflict-free)
#pragma unroll
    for (int i = 0; i < 2; ++i)
#pragma unroll
      for (int j = 0; j < 2; ++j)
        *(floatx4*)((char*)ztf + ((wave * 2 + i) * 2 + j) * 1024 + lane * 16) =
            acc[i][j];
    __syncthreads();

    // epilogue: thread handles (b_, jj) for b_ = q*32 + (tid>>3), jj = tid&7
    __hip_bfloat16* hout =
        hcat + (size_t)t_in * B_ * 2 * H_ + dir * H_ + j0 + jj;
#pragma unroll
    for (int q = 0; q < 4; ++q) {
      int b_ = q * 32 + (tid >> 3);
      int w = b_ >> 5, i = (b_ >> 4) & 1, q4 = (b_ >> 2) & 3, r = b_ & 3;
      float z[4];
#pragma unroll
      for (int g = 0; g < 4; ++g) {
        int c = g * 8 + jj;
        int j = c >> 4, c16 = c & 15;
        z[g] = ztf[(((w * 2 + i) * 2 + j) << 8) + (q4 * 16 + c16) * 4 + r];
      }
      float iv = 1.f / (1.f + __expf(-(z[0] + bi)));
      float fv = 1.f / (1.f + __expf(-(z[1] + bf2)));
      float ov = 1.f / (1.f + __expf(-(z[3] + bo)));
      float zg = z[2] + bg;
      float gv = dir ? fmaxf(zg, 0.f) : (1.f - 2.f / (__expf(2.f * zg) + 1.f));
      float c_ = fv * creg[q] + iv * gv;
      creg[q] = c_;
      float hv = dir ? (ov * fmaxf(c_, 0.f))
                     : (ov * (1.f - 2.f / (__expf(2.f * c_) + 1.f)));
      hout[(size_t)b_ * 2 * H_] = __float2bfloat16(hv);
    }

    // per-direction barrier (release h writes, acquire others')
    __syncthreads();
    if (tid == 0) {
      __threadfence();
      atomicAdd(ctr, 1);
      const int target = (t + 1) * 128;
      while (__hip_atomic_load(ctr, __ATOMIC_ACQUIRE,
                               __HIP_MEMORY_SCOPE_AGENT) < target)
        __builtin_amdgcn_s_sleep(1);
    }
    __syncthreads();
  }
}

// ---- dense: out[b][s][v] = hcat[s][b][:] @ Wd + bd ----
__global__ void __launch_bounds__(256, 1)
k_dense(const __hip_bfloat16* __restrict__ hcat,
        const __hip_bfloat16* __restrict__ WdT, const float* __restrict__ bd,
        void* __restrict__ outv, const int* __restrict__ flag) {
  bool f32 = flag[0] != 0;
  __shared__ __align__(16) unsigned char smem[16384];
  __hip_bfloat16* At = (__hip_bfloat16*)smem;
  __hip_bfloat16* Bt = (__hip_bfloat16*)(smem + 8192);
  const int tid = threadIdx.x, lane = tid & 63, wave = tid >> 6;
  const int wr = wave >> 1, wc = wave & 1;
  const int r0 = blockIdx.x * 128;
  const int n0 = blockIdx.y * 128;

  floatx4 acc[4][4] = {};
  int arow[2], akoff[2];
  for (int q = 0; q < 2; ++q) {
    int flat = (wave * 2 + q) * 1024 + lane * 16;
    arow[q] = flat >> 6;
    akoff[q] = (flat & 63) >> 1;
  }

  for (int kc = 0; kc < 64; ++kc) {
    for (int q = 0; q < 2; ++q) {
      const __hip_bfloat16* srcA =
          hcat + (size_t)(r0 + arow[q]) * 2048 + kc * 32 + akoff[q];
      GLD_LDS16(srcA, At + (wave * 2 + q) * 512);
      const __hip_bfloat16* srcB =
          WdT + (size_t)(n0 + arow[q]) * 2048 + kc * 32 + akoff[q];
      GLD_LDS16(srcB, Bt + (wave * 2 + q) * 512);
    }
    __syncthreads();
    bf16x8 a[4], b[4];
    const int k8 = (lane >> 4) * 8;
    for (int i = 0; i < 4; ++i) {
      int m = wr * 64 + i * 16 + (lane & 15);
      a[i] = *(const bf16x8*)((const char*)At + m * 64 + k8 * 2);
    }
    for (int j = 0; j < 4; ++j) {
      int n = wc * 64 + j * 16 + (lane & 15);
      b[j] = *(const bf16x8*)((const char*)Bt + n * 64 + k8 * 2);
    }
    for (int i = 0; i < 4; ++i)
      for (int j = 0; j < 4; ++j)
        acc[i][j] = MFMA16(a[i], b[j], acc[i][j]);
    __syncthreads();
  }

  for (int j = 0; j < 4; ++j) {
    int n = n0 + wc * 64 + j * 16 + (lane & 15);
    float bdv = bd[n];
    for (int i = 0; i < 4; ++i)
      for (int r = 0; r < 4; ++r) {
        int m = wr * 64 + i * 16 + (lane >> 4) * 4 + r;
        int row = r0 + m;
        int s = row >> 7, b_ = row & 127;
        size_t off = (size_t)b_ * S_ * V_ + (size_t)s * V_ + n;
        float val = acc[i][j][r] + bdv;
        if (f32)
          ((float*)outv)[off] = val;
        else
          ((__hip_bfloat16*)outv)[off] = __float2bfloat16(val);
      }
  }
}

extern "C" void kernel_launch(void* const* d_in, const int* in_sizes, int n_in,
                              void* d_out, int out_size, void* d_ws,
                              size_t ws_size, hipStream_t stream) {
  const int* tokens = (const int*)d_in[0];
  const void* emb = d_in[1];
  const void* Wf = d_in[2];
  const void* Uf = d_in[3];
  const void* bfv = d_in[4];
  const void* Wb = d_in[5];
  const void* Ub = d_in[6];
  const void* bbv = d_in[7];
  const void* Wd = d_in[8];
  const void* bd = d_in[9];

  char* ws = (char*)d_ws;
  int* flag = (int*)ws;                        // 4B @ 0
  int* ctr0 = (int*)(ws + 128);                // own cacheline
  int* ctr1 = (int*)(ws + 256);                // own cacheline
  float* biasws = (float*)(ws + 512);          // 10240 f32
  __hip_bfloat16* WTf = (__hip_bfloat16*)(ws + 512 + 40960);
  __hip_bfloat16* WTb = WTf + (size_t)4096 * 1536;
  __hip_bfloat16* WdT = WTb + (size_t)4096 * 1536;
  __hip_bfloat16* xt = WdT + (size_t)2048 * 2048;
  __hip_bfloat16* hcat = xt + (size_t)S_ * B_ * E_;  // [256][128][2048]

  hipMemsetAsync(ws + 128, 0, 384, stream);
  k_detect<<<1, 256, 0, stream>>>((const unsigned short*)emb, flag);
  k_bias<<<40, 256, 0, stream>>>(bfv, bbv, bd, biasws, flag);
  k_gather<<<8192, 256, 0, stream>>>(tokens, emb, xt, flag);
  k_transpose<<<dim3(64, 8), 256, 0, stream>>>(Wf, 512, 4096, WTf, KC_, 0, flag);
  k_transpose<<<dim3(64, 16), 256, 0, stream>>>(Uf, 1024, 4096, WTf, KC_, 512, flag);
  k_transpose<<<dim3(64, 8), 256, 0, stream>>>(Wb, 512, 4096, WTb, KC_, 0, flag);
  k_transpose<<<dim3(64, 16), 256, 0, stream>>>(Ub, 1024, 4096, WTb, KC_, 512, flag);
  k_transpose<<<dim3(32, 32), 256, 0, stream>>>(Wd, 2048, 2048, WdT, 2048, 0, flag);

  float* biasf_ws = biasws;
  float* biasb_ws = biasws + 4096;
  float* bd_ws = biasws + 8192;

  const int lstm_lds = 98304 + 16384;  // Blds + ztf = 112KB
  hipFuncSetAttribute((const void*)k_lstm,
                      hipFuncAttributeMaxDynamicSharedMemorySize, lstm_lds);
  void* args[] = {(void*)&xt,       (void*)&WTf,      (void*)&WTb,
                  (void*)&biasf_ws, (void*)&biasb_ws, (void*)&hcat,
                  (void*)&ctr0,     (void*)&ctr1};
  hipLaunchCooperativeKernel((void*)k_lstm, dim3(256), dim3(256), args,
                             lstm_lds, stream);

  k_dense<<<dim3(256, 16), 256, 0, stream>>>(hcat, WdT, bd_ws, d_out, flag);
}

// Round 4
// 6653.153 us; speedup vs baseline: 1.9081x; 1.3083x over previous
//
#include <hip/hip_runtime.h>
#include <hip/hip_bf16.h>
#include <hip/hip_cooperative_groups.h>

namespace cg = cooperative_groups;

typedef __bf16 bf16x8 __attribute__((ext_vector_type(8)));
typedef float floatx4 __attribute__((ext_vector_type(4)));

#define GLD_LDS16(g, s)                                              \
  __builtin_amdgcn_global_load_lds(                                  \
      (__attribute__((address_space(1))) void*)(g),                  \
      (__attribute__((address_space(3))) void*)(s), 16, 0, 0)

#define MFMA16(a, b, c) __builtin_amdgcn_mfma_f32_16x16x32_bf16(a, b, c, 0, 0, 0)

constexpr int B_ = 128, S_ = 256, E_ = 512, H_ = 1024, V_ = 2048;
constexpr int KC_ = E_ + H_;

// ---- dtype detect (bf16 vs fp32 inputs) ----
__global__ void k_detect(const unsigned short* __restrict__ emb,
                         int* __restrict__ flag) {
  __shared__ int cnt;
  if (threadIdx.x == 0) cnt = 0;
  __syncthreads();
  int local = 0;
  for (int i = threadIdx.x; i < 32768; i += 256) {
    unsigned int u = ((unsigned int)emb[i]) << 16;
    float v = __uint_as_float(u);
    if (!(fabsf(v) < 1.0f)) local++;
  }
  atomicAdd(&cnt, local);
  __syncthreads();
  if (threadIdx.x == 0) flag[0] = (cnt > 256) ? 1 : 0;
}

// ---- biases -> fp32 ws ----
__global__ void k_bias(const void* __restrict__ bfv, const void* __restrict__ bbv,
                       const void* __restrict__ bdv, float* __restrict__ biasws,
                       const int* __restrict__ flag) {
  bool f32 = flag[0] != 0;
  int i = blockIdx.x * 256 + threadIdx.x;
  if (i >= 10240) return;
  const void* src;
  int off;
  if (i < 4096) { src = bfv; off = i; }
  else if (i < 8192) { src = bbv; off = i - 4096; }
  else { src = bdv; off = i - 8192; }
  float v = f32 ? ((const float*)src)[off]
                : __bfloat162float(((const __hip_bfloat16*)src)[off]);
  biasws[i] = v;
}

// ---- gather ----
__global__ void k_gather(const int* __restrict__ tokens, const void* __restrict__ emb,
                         __hip_bfloat16* __restrict__ xt,
                         const int* __restrict__ flag) {
  bool f32 = flag[0] != 0;
  int idx = blockIdx.x * 256 + threadIdx.x;
  int e8 = idx & 63;
  int sb = idx >> 6;
  int s = sb >> 7;
  int b = sb & 127;
  int tok = tokens[b * S_ + s];
  uint4* dst = (uint4*)(xt + (size_t)sb * E_) + e8;
  if (f32) {
    const float* src = (const float*)emb + (size_t)tok * E_ + e8 * 8;
    float4 lo = ((const float4*)src)[0];
    float4 hi = ((const float4*)src)[1];
    __hip_bfloat16 v[8];
    v[0] = __float2bfloat16(lo.x); v[1] = __float2bfloat16(lo.y);
    v[2] = __float2bfloat16(lo.z); v[3] = __float2bfloat16(lo.w);
    v[4] = __float2bfloat16(hi.x); v[5] = __float2bfloat16(hi.y);
    v[6] = __float2bfloat16(hi.z); v[7] = __float2bfloat16(hi.w);
    *dst = *(const uint4*)v;
  } else {
    *dst = ((const uint4*)((const __hip_bfloat16*)emb + (size_t)tok * E_))[e8];
  }
}

// ---- transpose ----
__global__ void k_transpose(const void* __restrict__ in, int K, int N,
                            __hip_bfloat16* __restrict__ out, int ostride,
                            int ocol, const int* __restrict__ flag) {
  bool f32 = flag[0] != 0;
  __shared__ __hip_bfloat16 tile[64][65];
  int n0 = blockIdx.x * 64, k0 = blockIdx.y * 64;
  for (int i = 0; i < 16; ++i) {
    int flat = i * 256 + threadIdx.x;
    int kk = flat >> 6, nn = flat & 63;
    size_t off = (size_t)(k0 + kk) * N + n0 + nn;
    tile[kk][nn] = f32 ? __float2bfloat16(((const float*)in)[off])
                       : ((const __hip_bfloat16*)in)[off];
  }
  __syncthreads();
  for (int i = 0; i < 16; ++i) {
    int flat = i * 256 + threadIdx.x;
    int nn = flat >> 6, kk = flat & 63;
    out[(size_t)(n0 + nn) * ostride + ocol + k0 + kk] = tile[kk][nn];
  }
}

// ---- persistent bidirectional LSTM, weight-stationary, 512 thr/block ----
// 256 blocks: 0..127 fwd (tanh), 128..255 bwd (relu). Block owns 8 h-units
// (N=32 z-cols). Weights [32][1536] in LDS fragment order. 8 waves, wave
// tile M16xN32. Slot-array barrier; x-part of step t+1 computed after
// signaling step t (hides barrier wait).
__global__ void __launch_bounds__(512, 2)
k_lstm(const __hip_bfloat16* __restrict__ xt,
       const __hip_bfloat16* __restrict__ WTf,
       const __hip_bfloat16* __restrict__ WTb,
       const float* __restrict__ biasf, const float* __restrict__ biasb,
       __hip_bfloat16* __restrict__ hcat, int* __restrict__ slots0,
       int* __restrict__ slots1) {
  extern __shared__ __align__(16) unsigned char smem[];
  __hip_bfloat16* Blds = (__hip_bfloat16*)smem;  // 96 frags x 1KB
  float* ztf = (float*)(smem + 98304);           // 16 frags x 1KB

  const int tid = threadIdx.x, lane = tid & 63, wave = tid >> 6;
  const int dir = blockIdx.x >> 7;
  const int nb = blockIdx.x & 127;
  const int j0 = nb * 8;
  const __hip_bfloat16* WT = dir ? WTb : WTf;
  const float* bias = dir ? biasb : biasf;
  int* slots = dir ? slots1 : slots0;

  // stage weights (fragment order); 12 frags per wave
  for (int f = wave; f < 96; f += 8) {
    int kc = f >> 1, j = f & 1;
    int c = j * 16 + (lane & 15);
    int row = (c >> 3) * H_ + j0 + (c & 7);
    const __hip_bfloat16* src =
        WT + (size_t)row * KC_ + kc * 32 + ((lane >> 4) * 8);
    GLD_LDS16(src, (char*)Blds + (size_t)f * 1024);
  }

  const int jj = tid & 7;
  const int erow = tid >> 3;  // 0..63
  const float bi = bias[j0 + jj];
  const float bf2 = bias[H_ + j0 + jj];
  const float bg = bias[2 * H_ + j0 + jj];
  const float bo = bias[3 * H_ + j0 + jj];
  float creg[2] = {0.f, 0.f};

  const int m0 = wave * 16 + (lane & 15);
  const int k8 = (lane >> 4) * 8;
  __syncthreads();  // drains weight staging

  floatx4 acc[2];
  {  // x-part for t=0
    const int t_in = dir ? (S_ - 1) : 0;
    const __hip_bfloat16* xb =
        xt + (size_t)t_in * B_ * E_ + (size_t)m0 * E_ + k8;
    acc[0] = (floatx4)(0.f);
    acc[1] = (floatx4)(0.f);
#pragma unroll 8
    for (int kc = 0; kc < 16; ++kc) {
      bf16x8 a = *(const bf16x8*)(xb + kc * 32);
      bf16x8 b0 = *(const bf16x8*)((char*)Blds + (kc * 2 + 0) * 1024 + lane * 16);
      bf16x8 b1 = *(const bf16x8*)((char*)Blds + (kc * 2 + 1) * 1024 + lane * 16);
      acc[0] = MFMA16(a, b0, acc[0]);
      acc[1] = MFMA16(a, b1, acc[1]);
    }
  }

  for (int t = 0; t < S_; ++t) {
    const int t_in = dir ? (S_ - 1 - t) : t;
    const int t_prev = dir ? (t_in + 1) : (t_in - 1);

    if (t > 0) {
      if (wave == 0) {  // wait: all 128 slots >= t (parallel poll)
        while (true) {
          int v0 = __hip_atomic_load(slots + lane, __ATOMIC_RELAXED,
                                     __HIP_MEMORY_SCOPE_AGENT);
          int v1 = __hip_atomic_load(slots + 64 + lane, __ATOMIC_RELAXED,
                                     __HIP_MEMORY_SCOPE_AGENT);
          if (__all(v0 >= t && v1 >= t)) break;
          __builtin_amdgcn_s_sleep(1);
        }
        __threadfence();  // acquire: invalidate stale caches
      }
      __syncthreads();
      const __hip_bfloat16* hb = hcat + (size_t)t_prev * B_ * 2 * H_ +
                                 dir * H_ + (size_t)m0 * 2 * H_ + k8;
#pragma unroll 8
      for (int kc = 0; kc < 32; ++kc) {
        bf16x8 a = *(const bf16x8*)(hb + (size_t)kc * 32);
        bf16x8 b0 =
            *(const bf16x8*)((char*)Blds + ((16 + kc) * 2 + 0) * 1024 + lane * 16);
        bf16x8 b1 =
            *(const bf16x8*)((char*)Blds + ((16 + kc) * 2 + 1) * 1024 + lane * 16);
        acc[0] = MFMA16(a, b0, acc[0]);
        acc[1] = MFMA16(a, b1, acc[1]);
      }
    }

    // acc -> LDS fragment order
    *(floatx4*)((char*)ztf + (wave * 2 + 0) * 1024 + lane * 16) = acc[0];
    *(floatx4*)((char*)ztf + (wave * 2 + 1) * 1024 + lane * 16) = acc[1];
    __syncthreads();

    __hip_bfloat16* hout =
        hcat + (size_t)t_in * B_ * 2 * H_ + dir * H_ + j0 + jj;
#pragma unroll
    for (int q = 0; q < 2; ++q) {
      int b_ = erow + q * 64;
      int w = b_ >> 4, mm = b_ & 15;
      float z[4];
#pragma unroll
      for (int g = 0; g < 4; ++g) {
        int c = g * 8 + jj;
        z[g] = ztf[(w * 2 + (c >> 4)) * 256 + ((c & 15) + 16 * (mm >> 2)) * 4 +
                   (mm & 3)];
      }
      float iv = 1.f / (1.f + __expf(-(z[0] + bi)));
      float fv = 1.f / (1.f + __expf(-(z[1] + bf2)));
      float ov = 1.f / (1.f + __expf(-(z[3] + bo)));
      float zg = z[2] + bg;
      float gv = dir ? fmaxf(zg, 0.f) : (1.f - 2.f / (__expf(2.f * zg) + 1.f));
      float c_ = fv * creg[q] + iv * gv;
      creg[q] = c_;
      float hv = dir ? (ov * fmaxf(c_, 0.f))
                     : (ov * (1.f - 2.f / (__expf(2.f * c_) + 1.f)));
      hout[(size_t)b_ * 2 * H_] = __float2bfloat16(hv);
    }
    __syncthreads();  // all h stores drained to L2 (vmcnt(0) at barrier)

    if (tid == 0) {
      __threadfence();  // release: L2 writeback for cross-XCD visibility
      __hip_atomic_store(slots + nb, t + 1, __ATOMIC_RELAXED,
                         __HIP_MEMORY_SCOPE_AGENT);
    }

    if (t + 1 < S_) {  // x-part for next step: hides barrier wait
      const int tn = dir ? (S_ - 2 - t) : (t + 1);
      const __hip_bfloat16* xb =
          xt + (size_t)tn * B_ * E_ + (size_t)m0 * E_ + k8;
      acc[0] = (floatx4)(0.f);
      acc[1] = (floatx4)(0.f);
#pragma unroll 8
      for (int kc = 0; kc < 16; ++kc) {
        bf16x8 a = *(const bf16x8*)(xb + kc * 32);
        bf16x8 b0 =
            *(const bf16x8*)((char*)Blds + (kc * 2 + 0) * 1024 + lane * 16);
        bf16x8 b1 =
            *(const bf16x8*)((char*)Blds + (kc * 2 + 1) * 1024 + lane * 16);
        acc[0] = MFMA16(a, b0, acc[0]);
        acc[1] = MFMA16(a, b1, acc[1]);
      }
    }
  }
}

// ---- dense: out[b][s][v] = hcat[s][b][:] @ Wd + bd ----
__global__ void __launch_bounds__(256, 1)
k_dense(const __hip_bfloat16* __restrict__ hcat,
        const __hip_bfloat16* __restrict__ WdT, const float* __restrict__ bd,
        void* __restrict__ outv, const int* __restrict__ flag) {
  bool f32 = flag[0] != 0;
  __shared__ __align__(16) unsigned char smem[16384];
  __hip_bfloat16* At = (__hip_bfloat16*)smem;
  __hip_bfloat16* Bt = (__hip_bfloat16*)(smem + 8192);
  const int tid = threadIdx.x, lane = tid & 63, wave = tid >> 6;
  const int wr = wave >> 1, wc = wave & 1;
  const int r0 = blockIdx.x * 128;
  const int n0 = blockIdx.y * 128;

  floatx4 acc[4][4] = {};
  int arow[2], akoff[2];
  for (int q = 0; q < 2; ++q) {
    int flat = (wave * 2 + q) * 1024 + lane * 16;
    arow[q] = flat >> 6;
    akoff[q] = (flat & 63) >> 1;
  }

  for (int kc = 0; kc < 64; ++kc) {
    for (int q = 0; q < 2; ++q) {
      const __hip_bfloat16* srcA =
          hcat + (size_t)(r0 + arow[q]) * 2048 + kc * 32 + akoff[q];
      GLD_LDS16(srcA, At + (wave * 2 + q) * 512);
      const __hip_bfloat16* srcB =
          WdT + (size_t)(n0 + arow[q]) * 2048 + kc * 32 + akoff[q];
      GLD_LDS16(srcB, Bt + (wave * 2 + q) * 512);
    }
    __syncthreads();
    bf16x8 a[4], b[4];
    const int k8 = (lane >> 4) * 8;
    for (int i = 0; i < 4; ++i) {
      int m = wr * 64 + i * 16 + (lane & 15);
      a[i] = *(const bf16x8*)((const char*)At + m * 64 + k8 * 2);
    }
    for (int j = 0; j < 4; ++j) {
      int n = wc * 64 + j * 16 + (lane & 15);
      b[j] = *(const bf16x8*)((const char*)Bt + n * 64 + k8 * 2);
    }
    for (int i = 0; i < 4; ++i)
      for (int j = 0; j < 4; ++j)
        acc[i][j] = MFMA16(a[i], b[j], acc[i][j]);
    __syncthreads();
  }

  for (int j = 0; j < 4; ++j) {
    int n = n0 + wc * 64 + j * 16 + (lane & 15);
    float bdv = bd[n];
    for (int i = 0; i < 4; ++i)
      for (int r = 0; r < 4; ++r) {
        int m = wr * 64 + i * 16 + (lane >> 4) * 4 + r;
        int row = r0 + m;
        int s = row >> 7, b_ = row & 127;
        size_t off = (size_t)b_ * S_ * V_ + (size_t)s * V_ + n;
        float val = acc[i][j][r] + bdv;
        if (f32)
          ((float*)outv)[off] = val;
        else
          ((__hip_bfloat16*)outv)[off] = __float2bfloat16(val);
      }
  }
}

extern "C" void kernel_launch(void* const* d_in, const int* in_sizes, int n_in,
                              void* d_out, int out_size, void* d_ws,
                              size_t ws_size, hipStream_t stream) {
  const int* tokens = (const int*)d_in[0];
  const void* emb = d_in[1];
  const void* Wf = d_in[2];
  const void* Uf = d_in[3];
  const void* bfv = d_in[4];
  const void* Wb = d_in[5];
  const void* Ub = d_in[6];
  const void* bbv = d_in[7];
  const void* Wd = d_in[8];
  const void* bd = d_in[9];

  char* ws = (char*)d_ws;
  int* flag = (int*)ws;                      // 4B @ 0
  int* slots0 = (int*)(ws + 128);            // 128 ints
  int* slots1 = (int*)(ws + 1152);           // 128 ints
  float* biasws = (float*)(ws + 4096);       // 10240 f32
  __hip_bfloat16* WTf = (__hip_bfloat16*)(ws + 4096 + 40960);
  __hip_bfloat16* WTb = WTf + (size_t)4096 * 1536;
  __hip_bfloat16* WdT = WTb + (size_t)4096 * 1536;
  __hip_bfloat16* xt = WdT + (size_t)2048 * 2048;
  __hip_bfloat16* hcat = xt + (size_t)S_ * B_ * E_;  // [256][128][2048]

  hipMemsetAsync(ws + 128, 0, 4096 - 128, stream);
  k_detect<<<1, 256, 0, stream>>>((const unsigned short*)emb, flag);
  k_bias<<<40, 256, 0, stream>>>(bfv, bbv, bd, biasws, flag);
  k_gather<<<8192, 256, 0, stream>>>(tokens, emb, xt, flag);
  k_transpose<<<dim3(64, 8), 256, 0, stream>>>(Wf, 512, 4096, WTf, KC_, 0, flag);
  k_transpose<<<dim3(64, 16), 256, 0, stream>>>(Uf, 1024, 4096, WTf, KC_, 512, flag);
  k_transpose<<<dim3(64, 8), 256, 0, stream>>>(Wb, 512, 4096, WTb, KC_, 0, flag);
  k_transpose<<<dim3(64, 16), 256, 0, stream>>>(Ub, 1024, 4096, WTb, KC_, 512, flag);
  k_transpose<<<dim3(32, 32), 256, 0, stream>>>(Wd, 2048, 2048, WdT, 2048, 0, flag);

  float* biasf_ws = biasws;
  float* biasb_ws = biasws + 4096;
  float* bd_ws = biasws + 8192;

  const int lstm_lds = 98304 + 16384;  // 112KB
  hipFuncSetAttribute((const void*)k_lstm,
                      hipFuncAttributeMaxDynamicSharedMemorySize, lstm_lds);
  void* args[] = {(void*)&xt,       (void*)&WTf,      (void*)&WTb,
                  (void*)&biasf_ws, (void*)&biasb_ws, (void*)&hcat,
                  (void*)&slots0,   (void*)&slots1};
  hipLaunchCooperativeKernel((void*)k_lstm, dim3(256), dim3(512), args,
                             lstm_lds, stream);

  k_dense<<<dim3(256, 16), 256, 0, stream>>>(hcat, WdT, bd_ws, d_out, flag);
}